// Round 14
// baseline (669.236 us; speedup 1.0000x reference)
//
#include <hip/hip_runtime.h>
#include <hip/hip_bf16.h>
#include <cstdint>
#include <cstddef>

#define NATOM 20000
#define NEDGE 320000
#define DD 128
#define NSLOT 256
#define BN_EPS 1e-5f

typedef _Float16 f16x8 __attribute__((ext_vector_type(8)));   // 8 fp16 (4 VGPRs)
typedef _Float16 f16x4 __attribute__((ext_vector_type(4)));
typedef float f32x4  __attribute__((ext_vector_type(4)));

__device__ inline f16x8 cvt8h(const float* p) {
    float4 x = *(const float4*)p; float4 y = *(const float4*)(p + 4);
    f16x8 r;
    r[0]=(_Float16)x.x; r[1]=(_Float16)x.y; r[2]=(_Float16)x.z; r[3]=(_Float16)x.w;
    r[4]=(_Float16)y.x; r[5]=(_Float16)y.y; r[6]=(_Float16)y.z; r[7]=(_Float16)y.w;
    return r;
}
// hi/lo fp16 split: hi+lo carries ~21 mantissa bits (~fp32 for our ranges)
__device__ inline void cvt8hpair(const float* p, f16x8& hi, f16x8& lo) {
    float4 x = *(const float4*)p; float4 y = *(const float4*)(p + 4);
    float v[8] = {x.x, x.y, x.z, x.w, y.x, y.y, y.z, y.w};
#pragma unroll
    for (int i = 0; i < 8; ++i) {
        _Float16 h = (_Float16)v[i]; hi[i] = h;
        lo[i] = (_Float16)(v[i] - (float)h);
    }
}
#define MFMA(a,b,c) __builtin_amdgcn_mfma_f32_16x16x32_f16((a),(b),(c),0,0,0)

// ---------------------------------------------------------------------------
// v13 = v12 + coalesced-write epilogues (R13 counters showed WRITE_SIZE ~2x|Y|
// on kf: scalar 4B D-fragment stores -> partial-line L2 evictions -> RMW
// amplification). Fix: stage the f32 output tile in LDS (REUSING the existing
// staging buffers after a barrier; no LDS growth) and write Y with float4
// full-row coalesced stores. Bit-identical numerics; stats path untouched.
// Quarantined (unexonerated R6 suspects): Phase A1/B2 rewrite, shfl-stats.
// ws (floats): Vloc[1920000] | W3m[16384] | bfold[128] | a1,bb1,a2,bb2 |
// slots[4*NSLOT*128]; then (_Float16*): W1p[57344] Wvdp[16384] W2p[16384]
// W3mp[16384] Wmp[16384] Wvap[16384] WvapLo[16384].
// Pack: dst[((kk*8+ct)*64+lane)*8+j] = W[kk*32+8*(lane>>4)+j][ct*16+(lane&15)]
// ---------------------------------------------------------------------------

// Pack fp32 weight [Ksrc][Nsrc] into MFMA-frag-ordered fp16 (lo=residual).
__global__ __launch_bounds__(256) void kp_v13(const float* __restrict__ src,
                                              _Float16* __restrict__ dst,
                                              int Ksrc, int Nsrc, int Kpad, int lo) {
    int total = (Kpad / 32) * 8 * 64 * 8;
    for (int o = blockIdx.x * blockDim.x + threadIdx.x; o < total;
         o += gridDim.x * blockDim.x) {
        int j = o & 7, lane = (o >> 3) & 63, ct = (o >> 9) & 7, kk = o >> 12;
        int k = kk * 32 + (lane >> 4) * 8 + j;
        int c = ct * 16 + (lane & 15);
        float v = (k < Ksrc && c < Nsrc) ? src[(size_t)k * Nsrc + c] : 0.f;
        if (lo) v = v - (float)(_Float16)v;
        dst[o] = (_Float16)v;
    }
}

// Vloc = hV @ Wva + bva  (split-precision fp16 MFMA: Ah*Bh + Al*Bh + Ah*Bl)
__global__ __launch_bounds__(256) void kv_v13(const float* __restrict__ hV,
                                              const _Float16* __restrict__ Wvap,
                                              const _Float16* __restrict__ WvapLo,
                                              const float* __restrict__ bva,
                                              float* __restrict__ Vloc) {
    const int t = threadIdx.x, lane = t & 63, w = t >> 6;
    const int r0 = blockIdx.x * 32;
    f16x8 ah[2][4], al[2][4];
#pragma unroll
    for (int rt = 0; rt < 2; ++rt) {
        const float* rowp = hV + (size_t)(r0 + rt * 16 + (lane & 15)) * 128;
#pragma unroll
        for (int kk = 0; kk < 4; ++kk)
            cvt8hpair(rowp + kk * 32 + (lane >> 4) * 8, ah[rt][kk], al[rt][kk]);
    }
    f32x4 acc[2][2] = {};
#pragma unroll
    for (int ct2 = 0; ct2 < 2; ++ct2) {
        const int ct = w * 2 + ct2;
#pragma unroll
        for (int kk = 0; kk < 4; ++kk) {
            f16x8 bh = *(const f16x8*)(Wvap   + ((size_t)(kk * 8 + ct) * 64 + lane) * 8);
            f16x8 bl = *(const f16x8*)(WvapLo + ((size_t)(kk * 8 + ct) * 64 + lane) * 8);
            acc[0][ct2] = MFMA(ah[0][kk], bh, acc[0][ct2]);
            acc[1][ct2] = MFMA(ah[1][kk], bh, acc[1][ct2]);
            acc[0][ct2] = MFMA(al[0][kk], bh, acc[0][ct2]);
            acc[1][ct2] = MFMA(al[1][kk], bh, acc[1][ct2]);
            acc[0][ct2] = MFMA(ah[0][kk], bl, acc[0][ct2]);
            acc[1][ct2] = MFMA(ah[1][kk], bl, acc[1][ct2]);
        }
    }
#pragma unroll
    for (int ct2 = 0; ct2 < 2; ++ct2) {
        const int c = (w * 2 + ct2) * 16 + (lane & 15);
        if (c < 96) {
            const float bb = bva[c];
#pragma unroll
            for (int rt = 0; rt < 2; ++rt)
#pragma unroll
                for (int r = 0; r < 4; ++r) {
                    int e = rt * 16 + (lane >> 4) * 4 + r;
                    Vloc[(size_t)(r0 + e) * 96 + c] = acc[rt][ct2][r] + bb;
                }
        }
    }
}

__global__ __launch_bounds__(256) void kw_v13(const float* __restrict__ W3,
                                              const float* __restrict__ b3,
                                              const float* __restrict__ Wm,
                                              const float* __restrict__ bm,
                                              float* __restrict__ W3m,
                                              float* __restrict__ bfold) {
    int o = blockIdx.x * blockDim.x + threadIdx.x;
    if (o < 16384) {
        int k = o >> 7, c = o & 127;
        float acc = 0.f;
#pragma unroll 8
        for (int j = 0; j < 128; ++j) acc += W3[k * 128 + j] * Wm[(128 + j) * 128 + c];
        W3m[o] = acc;
    } else if (o < 16512) {
        int c = o - 16384;
        float acc = bm[c];
        for (int j = 0; j < 128; ++j) acc += b3[j] * Wm[(128 + j) * 128 + c];
        bfold[c] = acc;
    }
}

// Fused: geometric features (fp16 H tile in LDS) + V_edge MFMA + L1 MFMA.
__global__ __launch_bounds__(256, 5) void kf_v13(
        const float* __restrict__ hE, const float* __restrict__ rot,
        const float* __restrict__ trans, const float* __restrict__ rbf,
        const long long* __restrict__ eidx, const float* __restrict__ Vloc,
        const _Float16* __restrict__ Wvdp, const float* __restrict__ bvd,
        const _Float16* __restrict__ W1p, const float* __restrict__ b1,
        float* __restrict__ Y, float* __restrict__ gsum, float* __restrict__ gsq) {
    __shared__ alignas(16) _Float16 Hs[32][456];  // fp16 H tile; reused as f32 Y tile in epilogue
    __shared__ float rotS[32][9];
    __shared__ float trsS[32][3];
    __shared__ int srcI[32], dstI[32];
    __shared__ float bsum[128], bsq[128];

    const int t = threadIdx.x;
    const int e0 = blockIdx.x * 32;
    const int lane = t & 63, w = t >> 6;

    const int* e32a = (const int*)eidx;
    const bool is64 = (e32a[1] == 0) && (e32a[3] == 0) && (e32a[5] == 0);
    if (t < 32) {
        int s, d;
        if (is64) { s = (int)eidx[e0 + t]; d = (int)eidx[NEDGE + e0 + t]; }
        else      { s = e32a[e0 + t];      d = e32a[NEDGE + e0 + t]; }
        srcI[t] = min(max(s, 0), NATOM - 1);
        dstI[t] = min(max(d, 0), NATOM - 1);
    }
    if (t < 128) { bsum[t] = 0.f; bsq[t] = 0.f; }
    __syncthreads();

    // ---- hoisted long-latency register loads: hE rows (HBM) + Wvd frags (L2)
    f16x8 afr[2][4];
#pragma unroll
    for (int rt = 0; rt < 2; ++rt) {
        const float* rowp = hE + (size_t)(e0 + rt * 16 + (lane & 15)) * 128;
#pragma unroll
        for (int kk = 0; kk < 4; ++kk)
            afr[rt][kk] = cvt8h(rowp + kk * 32 + (lane >> 4) * 8);
    }
    f16x8 wb[2][4];
#pragma unroll
    for (int ct2 = 0; ct2 < 2; ++ct2)
#pragma unroll
        for (int kk = 0; kk < 4; ++kk)
            wb[ct2][kk] = *(const f16x8*)(Wvdp + ((size_t)(kk * 8 + w * 2 + ct2) * 64 + lane) * 8);

    // ---- Phase A: stage small features + Vs gather
    for (int o = t; o < 32 * 9; o += 256) {
        int e = o / 9, q = o % 9;
        float v = rot[(size_t)(e0 + e) * 9 + q];
        rotS[e][q] = v; Hs[e][384 + q] = (_Float16)v;
    }
    for (int o = t; o < 32 * 3; o += 256) {
        int e = o / 3, q = o % 3;
        trsS[e][q] = trans[(size_t)(e0 + e) * 3 + q];
    }
    for (int o = t; o < 32 * 16; o += 256) {
        int e = o >> 4, q = o & 15;
        Hs[e][393 + q] = (_Float16)rbf[(size_t)(e0 + e) * 16 + q];
    }
    for (int o = t; o < 32 * 15; o += 256) {    // zero K-pad cols 441..455
        int e = o / 15, q = o % 15;
        Hs[e][441 + q] = (_Float16)0.f;
    }
    for (int o = t; o < 32 * 96; o += 256) {
        int e = o / 96, c = o % 96;
        Hs[e][96 + c] = (_Float16)Vloc[(size_t)srcI[e] * 96 + c];
    }

    // ---- Phase B: V_edge = hE @ Wvd + bvd  (cols 0..95), frags preloaded
    {
        f32x4 acc[2][2] = {};
#pragma unroll
        for (int ct2 = 0; ct2 < 2; ++ct2)
#pragma unroll
            for (int kk = 0; kk < 4; ++kk) {
                acc[0][ct2] = MFMA(afr[0][kk], wb[ct2][kk], acc[0][ct2]);
                acc[1][ct2] = MFMA(afr[1][kk], wb[ct2][kk], acc[1][ct2]);
            }
#pragma unroll
        for (int ct2 = 0; ct2 < 2; ++ct2) {
            const int c = (w * 2 + ct2) * 16 + (lane & 15);
            if (c < 96) {
                const float bb = bvd[c];
#pragma unroll
                for (int rt = 0; rt < 2; ++rt)
#pragma unroll
                    for (int r = 0; r < 4; ++r) {
                        int e = rt * 16 + (lane >> 4) * 4 + r;
                        Hs[e][c] = (_Float16)(acc[rt][ct2][r] + bb);
                    }
            }
        }
    }
    __syncthreads();

    // ---- Phase C: Qt (cols 192..383) and QRK (cols 409..440)
    for (int o = t; o < 32 * 192; o += 256) {
        int e = o / 192, rem = o % 192, n = rem / 3, i = rem % 3;
        float acc = trsS[e][i];
#pragma unroll
        for (int j = 0; j < 3; ++j) acc += rotS[e][3 * i + j] * (float)Hs[e][n * 3 + j];
        Hs[e][192 + n * 3 + i] = (_Float16)acc;
    }
    for (int o = t; o < 32 * 32; o += 256) {
        int e = o >> 5, aa = o & 31;
        const float* vd = Vloc + (size_t)dstI[e] * 96 + aa * 3;  // fp32 Vd direct
        float q = 0.f;
#pragma unroll
        for (int i = 0; i < 3; ++i) {
            float rk = 0.f;
#pragma unroll
            for (int j = 0; j < 3; ++j) rk += rotS[e][3 * i + j] * (float)Hs[e][96 + aa * 3 + j];
            q += vd[i] * rk;
        }
        Hs[e][409 + aa] = (_Float16)q;
    }
    __syncthreads();

    // ---- Phase D: Y1 = H @ W1 + b1 (K=448), full unroll for deep prefetch
    {
        f32x4 acc[2][2] = {};
#pragma unroll
        for (int kk = 0; kk < 14; ++kk) {
            f16x8 a0 = *(const f16x8*)&Hs[(lane & 15)][kk * 32 + (lane >> 4) * 8];
            f16x8 a1 = *(const f16x8*)&Hs[16 + (lane & 15)][kk * 32 + (lane >> 4) * 8];
            f16x8 b0 = *(const f16x8*)(W1p + ((size_t)(kk * 8 + 2 * w) * 64 + lane) * 8);
            f16x8 b1v = *(const f16x8*)(W1p + ((size_t)(kk * 8 + 2 * w + 1) * 64 + lane) * 8);
            acc[0][0] = MFMA(a0, b0, acc[0][0]);
            acc[1][0] = MFMA(a1, b0, acc[1][0]);
            acc[0][1] = MFMA(a0, b1v, acc[0][1]);
            acc[1][1] = MFMA(a1, b1v, acc[1][1]);
        }
        // epilogue: stats on acc + LDS repack (reuse Hs) + coalesced write
        __syncthreads();   // all waves done reading Hs
        float (*Yl)[132] = (float(*)[132])(&Hs[0][0]);
#pragma unroll
        for (int ct2 = 0; ct2 < 2; ++ct2) {
            const int c = (2 * w + ct2) * 16 + (lane & 15);
            const float bias = b1[c];
#pragma unroll
            for (int rt = 0; rt < 2; ++rt) {
                float s = 0.f, sq = 0.f;
#pragma unroll
                for (int r = 0; r < 4; ++r) {
                    int e = rt * 16 + (lane >> 4) * 4 + r;
                    float y = acc[rt][ct2][r] + bias;
                    Yl[e][c] = y;
                    s += y; sq += y * y;
                }
                atomicAdd(&bsum[c], s);
                atomicAdd(&bsq[c], sq);
            }
        }
        __syncthreads();
        for (int o = t; o < 32 * 32; o += 256) {
            int e = o >> 5, k4 = (o & 31) << 2;
            *(float4*)&Y[(size_t)(e0 + e) * 128 + k4] = *(const float4*)&Yl[e][k4];
        }
    }
    if (t < 128) {
        const int slot = blockIdx.x & (NSLOT - 1);
        atomicAdd(&gsum[slot * 128 + t], bsum[t]);
        atomicAdd(&gsq[slot * 128 + t], bsq[t]);
    }
}

__global__ __launch_bounds__(128) void ks_v13(const float* __restrict__ gsum,
                                              const float* __restrict__ gsq,
                                              const float* __restrict__ g,
                                              const float* __restrict__ be,
                                              float* __restrict__ a,
                                              float* __restrict__ bb) {
    const int c = threadIdx.x;
    float S = 0.f, Q = 0.f;
    for (int s = 0; s < NSLOT; ++s) { S += gsum[s * 128 + c]; Q += gsq[s * 128 + c]; }
    const float mean = S / (float)NEDGE;
    const float var  = Q / (float)NEDGE - mean * mean;
    const float av   = g[c] * rsqrtf(var + BN_EPS);
    a[c]  = av;
    bb[c] = be[c] - mean * av;
}

// Y2 = relu(bn1(Y1)) @ W2 + b2 (MFMA), in place; accumulate BN2 stats.
__global__ __launch_bounds__(256, 6) void k2_v13(float* __restrict__ Y,
                                                 const float* __restrict__ a1,
                                                 const float* __restrict__ bb1,
                                                 const _Float16* __restrict__ W2p,
                                                 const float* __restrict__ b2,
                                                 float* __restrict__ gsum,
                                                 float* __restrict__ gsq) {
    __shared__ alignas(16) _Float16 XH[2][32][136];  // [0]=Xs; whole buf reused as f32 Y tile
    __shared__ float bsum[128], bsq[128];
    const int t = threadIdx.x, lane = t & 63, w = t >> 6;
    const int e0 = blockIdx.x * 32;
    if (t < 128) { bsum[t] = 0.f; bsq[t] = 0.f; }
    for (int o = t; o < 32 * 32; o += 256) {   // vectorized staging
        int e = o >> 5, k4 = (o & 31) << 2;
        float4 v = *(const float4*)&Y[(size_t)(e0 + e) * 128 + k4];
        float4 av = *(const float4*)&a1[k4];
        float4 bv = *(const float4*)&bb1[k4];
        f16x4 s;
        s[0] = (_Float16)fmaxf(v.x * av.x + bv.x, 0.f);
        s[1] = (_Float16)fmaxf(v.y * av.y + bv.y, 0.f);
        s[2] = (_Float16)fmaxf(v.z * av.z + bv.z, 0.f);
        s[3] = (_Float16)fmaxf(v.w * av.w + bv.w, 0.f);
        *(f16x4*)&XH[0][e][k4] = s;
    }
    __syncthreads();
    f32x4 acc[2][2] = {};
#pragma unroll
    for (int kk = 0; kk < 4; ++kk) {
        f16x8 a0 = *(const f16x8*)&XH[0][(lane & 15)][kk * 32 + (lane >> 4) * 8];
        f16x8 a1f = *(const f16x8*)&XH[0][16 + (lane & 15)][kk * 32 + (lane >> 4) * 8];
        f16x8 b0 = *(const f16x8*)(W2p + ((size_t)(kk * 8 + 2 * w) * 64 + lane) * 8);
        f16x8 b1v = *(const f16x8*)(W2p + ((size_t)(kk * 8 + 2 * w + 1) * 64 + lane) * 8);
        acc[0][0] = MFMA(a0, b0, acc[0][0]);
        acc[1][0] = MFMA(a1f, b0, acc[1][0]);
        acc[0][1] = MFMA(a0, b1v, acc[0][1]);
        acc[1][1] = MFMA(a1f, b1v, acc[1][1]);
    }
    __syncthreads();   // staging reads done; reuse XH as f32 tile
    float (*Yl)[132] = (float(*)[132])(&XH[0][0][0]);
#pragma unroll
    for (int ct2 = 0; ct2 < 2; ++ct2) {
        const int c = (2 * w + ct2) * 16 + (lane & 15);
        const float bias = b2[c];
#pragma unroll
        for (int rt = 0; rt < 2; ++rt) {
            float s = 0.f, sq = 0.f;
#pragma unroll
            for (int r = 0; r < 4; ++r) {
                int e = rt * 16 + (lane >> 4) * 4 + r;
                float y = acc[rt][ct2][r] + bias;
                Yl[e][c] = y;
                s += y; sq += y * y;
            }
            atomicAdd(&bsum[c], s);
            atomicAdd(&bsq[c], sq);
        }
    }
    __syncthreads();
    for (int o = t; o < 32 * 32; o += 256) {
        int e = o >> 5, k4 = (o & 31) << 2;
        *(float4*)&Y[(size_t)(e0 + e) * 128 + k4] = *(const float4*)&Yl[e][k4];
    }
    if (t < 128) {
        const int slot = blockIdx.x & (NSLOT - 1);
        atomicAdd(&gsum[slot * 128 + t], bsum[t]);
        atomicAdd(&gsq[slot * 128 + t], bsq[t]);
    }
}

// out = relu(bn2(Y2)) @ W3m + hE @ WmTop + bfold (two fused MFMA GEMMs).
__global__ __launch_bounds__(256, 6) void k3_v13(float* __restrict__ Y,
                                                 const float* __restrict__ hE,
                                                 const float* __restrict__ a2,
                                                 const float* __restrict__ bb2,
                                                 const _Float16* __restrict__ W3mp,
                                                 const _Float16* __restrict__ Wmp,
                                                 const float* __restrict__ bfold) {
    __shared__ alignas(16) _Float16 XH[2][32][136];  // [0]=Xs, [1]=Hes; reused as f32 Y tile
    const int t = threadIdx.x, lane = t & 63, w = t >> 6;
    const int e0 = blockIdx.x * 32;
    for (int o = t; o < 32 * 32; o += 256) {   // vectorized staging
        int e = o >> 5, k4 = (o & 31) << 2;
        float4 v = *(const float4*)&Y[(size_t)(e0 + e) * 128 + k4];
        float4 hv = *(const float4*)&hE[(size_t)(e0 + e) * 128 + k4];
        float4 av = *(const float4*)&a2[k4];
        float4 bv = *(const float4*)&bb2[k4];
        f16x4 s, h;
        s[0] = (_Float16)fmaxf(v.x * av.x + bv.x, 0.f);
        s[1] = (_Float16)fmaxf(v.y * av.y + bv.y, 0.f);
        s[2] = (_Float16)fmaxf(v.z * av.z + bv.z, 0.f);
        s[3] = (_Float16)fmaxf(v.w * av.w + bv.w, 0.f);
        h[0] = (_Float16)hv.x; h[1] = (_Float16)hv.y;
        h[2] = (_Float16)hv.z; h[3] = (_Float16)hv.w;
        *(f16x4*)&XH[0][e][k4] = s;
        *(f16x4*)&XH[1][e][k4] = h;
    }
    __syncthreads();
    f32x4 acc[2][2] = {};
#pragma unroll
    for (int kk = 0; kk < 4; ++kk) {
        f16x8 x0 = *(const f16x8*)&XH[0][(lane & 15)][kk * 32 + (lane >> 4) * 8];
        f16x8 x1 = *(const f16x8*)&XH[0][16 + (lane & 15)][kk * 32 + (lane >> 4) * 8];
        f16x8 h0 = *(const f16x8*)&XH[1][(lane & 15)][kk * 32 + (lane >> 4) * 8];
        f16x8 h1 = *(const f16x8*)&XH[1][16 + (lane & 15)][kk * 32 + (lane >> 4) * 8];
        f16x8 w30 = *(const f16x8*)(W3mp + ((size_t)(kk * 8 + 2 * w) * 64 + lane) * 8);
        f16x8 w31 = *(const f16x8*)(W3mp + ((size_t)(kk * 8 + 2 * w + 1) * 64 + lane) * 8);
        f16x8 wm0 = *(const f16x8*)(Wmp + ((size_t)(kk * 8 + 2 * w) * 64 + lane) * 8);
        f16x8 wm1 = *(const f16x8*)(Wmp + ((size_t)(kk * 8 + 2 * w + 1) * 64 + lane) * 8);
        acc[0][0] = MFMA(x0, w30, acc[0][0]);
        acc[1][0] = MFMA(x1, w30, acc[1][0]);
        acc[0][1] = MFMA(x0, w31, acc[0][1]);
        acc[1][1] = MFMA(x1, w31, acc[1][1]);
        acc[0][0] = MFMA(h0, wm0, acc[0][0]);
        acc[1][0] = MFMA(h1, wm0, acc[1][0]);
        acc[0][1] = MFMA(h0, wm1, acc[0][1]);
        acc[1][1] = MFMA(h1, wm1, acc[1][1]);
    }
    __syncthreads();   // staging reads done; reuse XH as f32 tile
    float (*Yl)[132] = (float(*)[132])(&XH[0][0][0]);
#pragma unroll
    for (int ct2 = 0; ct2 < 2; ++ct2) {
        const int c = (2 * w + ct2) * 16 + (lane & 15);
        const float bias = bfold[c];
#pragma unroll
        for (int rt = 0; rt < 2; ++rt)
#pragma unroll
            for (int r = 0; r < 4; ++r) {
                int e = rt * 16 + (lane >> 4) * 4 + r;
                Yl[e][c] = acc[rt][ct2][r] + bias;
            }
    }
    __syncthreads();
    for (int o = t; o < 32 * 32; o += 256) {
        int e = o >> 5, k4 = (o & 31) << 2;
        *(float4*)&Y[(size_t)(e0 + e) * 128 + k4] = *(const float4*)&Yl[e][k4];
    }
}

extern "C" void kernel_launch(void* const* d_in, const int* in_sizes, int n_in,
                              void* d_out, int out_size, void* d_ws, size_t ws_size,
                              hipStream_t stream) {
    const float* hV    = (const float*)d_in[0];
    const float* hE    = (const float*)d_in[1];
    const float* rot   = (const float*)d_in[2];
    const float* trans = (const float*)d_in[3];
    const float* rbf   = (const float*)d_in[4];
    const float* Wva   = (const float*)d_in[6];
    const float* bva   = (const float*)d_in[7];
    const float* Wvd   = (const float*)d_in[8];
    const float* bvd   = (const float*)d_in[9];
    const float* W1    = (const float*)d_in[10];
    const float* b1    = (const float*)d_in[11];
    const float* g1    = (const float*)d_in[12];
    const float* be1   = (const float*)d_in[13];
    const float* W2    = (const float*)d_in[14];
    const float* b2    = (const float*)d_in[15];
    const float* g2    = (const float*)d_in[16];
    const float* be2   = (const float*)d_in[17];
    const float* W3    = (const float*)d_in[18];
    const float* b3    = (const float*)d_in[19];
    const float* Wm    = (const float*)d_in[20];
    const float* bm    = (const float*)d_in[21];
    const long long* eidx = (const long long*)d_in[22];

    float* ws    = (float*)d_ws;
    float* Vloc  = ws;
    float* W3m   = ws + 1920000;
    float* bfold = W3m + 16384;
    float* a1    = bfold + 128;
    float* bb1   = a1 + 128;
    float* a2    = bb1 + 128;
    float* bb2   = a2 + 128;
    float* slots = bb2 + 128;
    float* gsum1 = slots;
    float* gsq1  = slots + NSLOT * 128;
    float* gsum2 = slots + 2 * NSLOT * 128;
    float* gsq2  = slots + 3 * NSLOT * 128;
    _Float16* W1p    = (_Float16*)(slots + 4 * NSLOT * 128);
    _Float16* Wvdp   = W1p + 57344;
    _Float16* W2p    = Wvdp + 16384;
    _Float16* W3mp   = W2p + 16384;
    _Float16* Wmp    = W3mp + 16384;
    _Float16* Wvap   = Wmp + 16384;
    _Float16* WvapLo = Wvap + 16384;
    float* Y     = (float*)d_out;

    hipMemsetAsync(slots, 0, (size_t)4 * NSLOT * 128 * sizeof(float), stream);
    kp_v13<<<64, 256, 0, stream>>>(Wva, Wvap, 128, 96, 128, 0);
    kp_v13<<<64, 256, 0, stream>>>(Wva, WvapLo, 128, 96, 128, 1);
    kw_v13<<<65, 256, 0, stream>>>(W3, b3, Wm, bm, W3m, bfold);
    kv_v13<<<NATOM / 32, 256, 0, stream>>>(hV, Wvap, WvapLo, bva, Vloc);
    kp_v13<<<224, 256, 0, stream>>>(W1, W1p, 441, 128, 448, 0);
    kp_v13<<<64, 256, 0, stream>>>(Wvd, Wvdp, 128, 96, 128, 0);
    kp_v13<<<64, 256, 0, stream>>>(W2, W2p, 128, 128, 128, 0);
    kp_v13<<<64, 256, 0, stream>>>(W3m, W3mp, 128, 128, 128, 0);
    kp_v13<<<64, 256, 0, stream>>>(Wm, Wmp, 128, 128, 128, 0);
    kf_v13<<<NEDGE / 32, 256, 0, stream>>>(hE, rot, trans, rbf, eidx, Vloc,
                                           Wvdp, bvd, W1p, b1, Y, gsum1, gsq1);
    ks_v13<<<1, 128, 0, stream>>>(gsum1, gsq1, g1, be1, a1, bb1);
    k2_v13<<<NEDGE / 32, 256, 0, stream>>>(Y, a1, bb1, W2p, b2, gsum2, gsq2);
    ks_v13<<<1, 128, 0, stream>>>(gsum2, gsq2, g2, be2, a2, bb2);
    k3_v13<<<NEDGE / 32, 256, 0, stream>>>(Y, hE, a2, bb2, W3mp, Wmp, bfold);
}

// Round 16
// 631.680 us; speedup vs baseline: 1.0595x; 1.0595x over previous
//
#include <hip/hip_runtime.h>
#include <hip/hip_bf16.h>
#include <cstdint>
#include <cstddef>

#define NATOM 20000
#define NEDGE 320000
#define DD 128
#define NSLOT 256
#define BN_EPS 1e-5f

typedef _Float16 f16x8 __attribute__((ext_vector_type(8)));   // 8 fp16 (4 VGPRs)
typedef _Float16 f16x4 __attribute__((ext_vector_type(4)));
typedef float f32x4  __attribute__((ext_vector_type(4)));

__device__ inline f16x8 cvt8h(const float* p) {
    float4 x = *(const float4*)p; float4 y = *(const float4*)(p + 4);
    f16x8 r;
    r[0]=(_Float16)x.x; r[1]=(_Float16)x.y; r[2]=(_Float16)x.z; r[3]=(_Float16)x.w;
    r[4]=(_Float16)y.x; r[5]=(_Float16)y.y; r[6]=(_Float16)y.z; r[7]=(_Float16)y.w;
    return r;
}
// hi/lo fp16 split: hi+lo carries ~21 mantissa bits (~fp32 for our ranges)
__device__ inline void cvt8hpair(const float* p, f16x8& hi, f16x8& lo) {
    float4 x = *(const float4*)p; float4 y = *(const float4*)(p + 4);
    float v[8] = {x.x, x.y, x.z, x.w, y.x, y.y, y.z, y.w};
#pragma unroll
    for (int i = 0; i < 8; ++i) {
        _Float16 h = (_Float16)v[i]; hi[i] = h;
        lo[i] = (_Float16)(v[i] - (float)h);
    }
}
#define MFMA(a,b,c) __builtin_amdgcn_mfma_f32_16x16x32_f16((a),(b),(c),0,0,0)

// ---------------------------------------------------------------------------
// v14 = v12 minus the register spill. R14 evidence: v13's fully-coalesced
// float4 row stores left WRITE_SIZE at exactly 330000 KB -> store pattern
// exonerated. The v11->v12 deltas (+160000 KB WRITE = 64B x 256thr x 10000blk,
// +85 MB FETCH, VGPR 64->48 while ADDING 32 hoisted regs) are a spill
// signature: hoisted afr/wb live ranges + launch_bounds(256,5) forced a
// 16-reg spill to scratch, which thrashes per-XCD L2 against the hE/Y streams.
// Fix: (1) afr/wb loads back INSIDE Phase B (v11 placement, short ranges);
// (2) launch_bounds(256,4) (cap 128 VGPR, LDS still gives 5 blocks/CU);
// (3) epilogues = direct scalar stores (v12 style, no extra barriers).
// Keep Vd-direct Phase C; its true FETCH cost is measurable once spill
// traffic is gone. Quarantined (R6 suspects): Phase A1/B2 rewrite, shfl-stats.
// ws (floats): Vloc[1920000] | W3m[16384] | bfold[128] | a1,bb1,a2,bb2 |
// slots[4*NSLOT*128]; then (_Float16*): W1p[57344] Wvdp[16384] W2p[16384]
// W3mp[16384] Wmp[16384] Wvap[16384] WvapLo[16384].
// Pack: dst[((kk*8+ct)*64+lane)*8+j] = W[kk*32+8*(lane>>4)+j][ct*16+(lane&15)]
// ---------------------------------------------------------------------------

// Pack fp32 weight [Ksrc][Nsrc] into MFMA-frag-ordered fp16 (lo=residual).
__global__ __launch_bounds__(256) void kp_v14(const float* __restrict__ src,
                                              _Float16* __restrict__ dst,
                                              int Ksrc, int Nsrc, int Kpad, int lo) {
    int total = (Kpad / 32) * 8 * 64 * 8;
    for (int o = blockIdx.x * blockDim.x + threadIdx.x; o < total;
         o += gridDim.x * blockDim.x) {
        int j = o & 7, lane = (o >> 3) & 63, ct = (o >> 9) & 7, kk = o >> 12;
        int k = kk * 32 + (lane >> 4) * 8 + j;
        int c = ct * 16 + (lane & 15);
        float v = (k < Ksrc && c < Nsrc) ? src[(size_t)k * Nsrc + c] : 0.f;
        if (lo) v = v - (float)(_Float16)v;
        dst[o] = (_Float16)v;
    }
}

// Vloc = hV @ Wva + bva  (split-precision fp16 MFMA: Ah*Bh + Al*Bh + Ah*Bl)
__global__ __launch_bounds__(256) void kv_v14(const float* __restrict__ hV,
                                              const _Float16* __restrict__ Wvap,
                                              const _Float16* __restrict__ WvapLo,
                                              const float* __restrict__ bva,
                                              float* __restrict__ Vloc) {
    const int t = threadIdx.x, lane = t & 63, w = t >> 6;
    const int r0 = blockIdx.x * 32;
    f16x8 ah[2][4], al[2][4];
#pragma unroll
    for (int rt = 0; rt < 2; ++rt) {
        const float* rowp = hV + (size_t)(r0 + rt * 16 + (lane & 15)) * 128;
#pragma unroll
        for (int kk = 0; kk < 4; ++kk)
            cvt8hpair(rowp + kk * 32 + (lane >> 4) * 8, ah[rt][kk], al[rt][kk]);
    }
    f32x4 acc[2][2] = {};
#pragma unroll
    for (int ct2 = 0; ct2 < 2; ++ct2) {
        const int ct = w * 2 + ct2;
#pragma unroll
        for (int kk = 0; kk < 4; ++kk) {
            f16x8 bh = *(const f16x8*)(Wvap   + ((size_t)(kk * 8 + ct) * 64 + lane) * 8);
            f16x8 bl = *(const f16x8*)(WvapLo + ((size_t)(kk * 8 + ct) * 64 + lane) * 8);
            acc[0][ct2] = MFMA(ah[0][kk], bh, acc[0][ct2]);
            acc[1][ct2] = MFMA(ah[1][kk], bh, acc[1][ct2]);
            acc[0][ct2] = MFMA(al[0][kk], bh, acc[0][ct2]);
            acc[1][ct2] = MFMA(al[1][kk], bh, acc[1][ct2]);
            acc[0][ct2] = MFMA(ah[0][kk], bl, acc[0][ct2]);
            acc[1][ct2] = MFMA(ah[1][kk], bl, acc[1][ct2]);
        }
    }
#pragma unroll
    for (int ct2 = 0; ct2 < 2; ++ct2) {
        const int c = (w * 2 + ct2) * 16 + (lane & 15);
        if (c < 96) {
            const float bb = bva[c];
#pragma unroll
            for (int rt = 0; rt < 2; ++rt)
#pragma unroll
                for (int r = 0; r < 4; ++r) {
                    int e = rt * 16 + (lane >> 4) * 4 + r;
                    Vloc[(size_t)(r0 + e) * 96 + c] = acc[rt][ct2][r] + bb;
                }
        }
    }
}

__global__ __launch_bounds__(256) void kw_v14(const float* __restrict__ W3,
                                              const float* __restrict__ b3,
                                              const float* __restrict__ Wm,
                                              const float* __restrict__ bm,
                                              float* __restrict__ W3m,
                                              float* __restrict__ bfold) {
    int o = blockIdx.x * blockDim.x + threadIdx.x;
    if (o < 16384) {
        int k = o >> 7, c = o & 127;
        float acc = 0.f;
#pragma unroll 8
        for (int j = 0; j < 128; ++j) acc += W3[k * 128 + j] * Wm[(128 + j) * 128 + c];
        W3m[o] = acc;
    } else if (o < 16512) {
        int c = o - 16384;
        float acc = bm[c];
        for (int j = 0; j < 128; ++j) acc += b3[j] * Wm[(128 + j) * 128 + c];
        bfold[c] = acc;
    }
}

// Fused: geometric features (fp16 H tile in LDS) + V_edge MFMA + L1 MFMA.
__global__ __launch_bounds__(256, 4) void kf_v14(
        const float* __restrict__ hE, const float* __restrict__ rot,
        const float* __restrict__ trans, const float* __restrict__ rbf,
        const long long* __restrict__ eidx, const float* __restrict__ Vloc,
        const _Float16* __restrict__ Wvdp, const float* __restrict__ bvd,
        const _Float16* __restrict__ W1p, const float* __restrict__ b1,
        float* __restrict__ Y, float* __restrict__ gsum, float* __restrict__ gsq) {
    __shared__ _Float16 Hs[32][456];   // fp16 H tile, cols 0..440 used, 441..447 zero
    __shared__ float rotS[32][9];
    __shared__ float trsS[32][3];
    __shared__ int srcI[32], dstI[32];
    __shared__ float bsum[128], bsq[128];

    const int t = threadIdx.x;
    const int e0 = blockIdx.x * 32;
    const int lane = t & 63, w = t >> 6;

    const int* e32a = (const int*)eidx;
    const bool is64 = (e32a[1] == 0) && (e32a[3] == 0) && (e32a[5] == 0);
    if (t < 32) {
        int s, d;
        if (is64) { s = (int)eidx[e0 + t]; d = (int)eidx[NEDGE + e0 + t]; }
        else      { s = e32a[e0 + t];      d = e32a[NEDGE + e0 + t]; }
        srcI[t] = min(max(s, 0), NATOM - 1);
        dstI[t] = min(max(d, 0), NATOM - 1);
    }
    if (t < 128) { bsum[t] = 0.f; bsq[t] = 0.f; }
    __syncthreads();

    // ---- Phase A: stage small features + Vs gather
    for (int o = t; o < 32 * 9; o += 256) {
        int e = o / 9, q = o % 9;
        float v = rot[(size_t)(e0 + e) * 9 + q];
        rotS[e][q] = v; Hs[e][384 + q] = (_Float16)v;
    }
    for (int o = t; o < 32 * 3; o += 256) {
        int e = o / 3, q = o % 3;
        trsS[e][q] = trans[(size_t)(e0 + e) * 3 + q];
    }
    for (int o = t; o < 32 * 16; o += 256) {
        int e = o >> 4, q = o & 15;
        Hs[e][393 + q] = (_Float16)rbf[(size_t)(e0 + e) * 16 + q];
    }
    for (int o = t; o < 32 * 15; o += 256) {    // zero K-pad cols 441..455
        int e = o / 15, q = o % 15;
        Hs[e][441 + q] = (_Float16)0.f;
    }
    for (int o = t; o < 32 * 96; o += 256) {
        int e = o / 96, c = o % 96;
        Hs[e][96 + c] = (_Float16)Vloc[(size_t)srcI[e] * 96 + c];
    }

    // ---- Phase B: V_edge = hE @ Wvd + bvd  (cols 0..95); loads in-phase
    {
        f16x8 a[2][4];
#pragma unroll
        for (int rt = 0; rt < 2; ++rt) {
            const float* rowp = hE + (size_t)(e0 + rt * 16 + (lane & 15)) * 128;
#pragma unroll
            for (int kk = 0; kk < 4; ++kk)
                a[rt][kk] = cvt8h(rowp + kk * 32 + (lane >> 4) * 8);
        }
        f32x4 acc[2][2] = {};
#pragma unroll
        for (int ct2 = 0; ct2 < 2; ++ct2) {
            const int ct = w * 2 + ct2;
#pragma unroll
            for (int kk = 0; kk < 4; ++kk) {
                f16x8 b = *(const f16x8*)(Wvdp + ((size_t)(kk * 8 + ct) * 64 + lane) * 8);
                acc[0][ct2] = MFMA(a[0][kk], b, acc[0][ct2]);
                acc[1][ct2] = MFMA(a[1][kk], b, acc[1][ct2]);
            }
        }
#pragma unroll
        for (int ct2 = 0; ct2 < 2; ++ct2) {
            const int c = (w * 2 + ct2) * 16 + (lane & 15);
            if (c < 96) {
                const float bb = bvd[c];
#pragma unroll
                for (int rt = 0; rt < 2; ++rt)
#pragma unroll
                    for (int r = 0; r < 4; ++r) {
                        int e = rt * 16 + (lane >> 4) * 4 + r;
                        Hs[e][c] = (_Float16)(acc[rt][ct2][r] + bb);
                    }
            }
        }
    }
    __syncthreads();

    // ---- Phase C: Qt (cols 192..383) and QRK (cols 409..440)
    for (int o = t; o < 32 * 192; o += 256) {
        int e = o / 192, rem = o % 192, n = rem / 3, i = rem % 3;
        float acc = trsS[e][i];
#pragma unroll
        for (int j = 0; j < 3; ++j) acc += rotS[e][3 * i + j] * (float)Hs[e][n * 3 + j];
        Hs[e][192 + n * 3 + i] = (_Float16)acc;
    }
    for (int o = t; o < 32 * 32; o += 256) {
        int e = o >> 5, aa = o & 31;
        const float* vd = Vloc + (size_t)dstI[e] * 96 + aa * 3;  // fp32 Vd direct
        float q = 0.f;
#pragma unroll
        for (int i = 0; i < 3; ++i) {
            float rk = 0.f;
#pragma unroll
            for (int j = 0; j < 3; ++j) rk += rotS[e][3 * i + j] * (float)Hs[e][96 + aa * 3 + j];
            q += vd[i] * rk;
        }
        Hs[e][409 + aa] = (_Float16)q;
    }
    __syncthreads();

    // ---- Phase D: Y1 = H @ W1 + b1 (K=448), direct scalar epilogue
    {
        f32x4 acc[2][2] = {};
#pragma unroll
        for (int kk = 0; kk < 14; ++kk) {
            f16x8 a0 = *(const f16x8*)&Hs[(lane & 15)][kk * 32 + (lane >> 4) * 8];
            f16x8 a1 = *(const f16x8*)&Hs[16 + (lane & 15)][kk * 32 + (lane >> 4) * 8];
            f16x8 b0 = *(const f16x8*)(W1p + ((size_t)(kk * 8 + 2 * w) * 64 + lane) * 8);
            f16x8 b1v = *(const f16x8*)(W1p + ((size_t)(kk * 8 + 2 * w + 1) * 64 + lane) * 8);
            acc[0][0] = MFMA(a0, b0, acc[0][0]);
            acc[1][0] = MFMA(a1, b0, acc[1][0]);
            acc[0][1] = MFMA(a0, b1v, acc[0][1]);
            acc[1][1] = MFMA(a1, b1v, acc[1][1]);
        }
#pragma unroll
        for (int ct2 = 0; ct2 < 2; ++ct2) {
            const int c = (2 * w + ct2) * 16 + (lane & 15);
            const float bias = b1[c];
#pragma unroll
            for (int rt = 0; rt < 2; ++rt) {
                float s = 0.f, sq = 0.f;
#pragma unroll
                for (int r = 0; r < 4; ++r) {
                    int e = rt * 16 + (lane >> 4) * 4 + r;
                    float y = acc[rt][ct2][r] + bias;
                    Y[(size_t)(e0 + e) * 128 + c] = y;
                    s += y; sq += y * y;
                }
                atomicAdd(&bsum[c], s);
                atomicAdd(&bsq[c], sq);
            }
        }
    }
    __syncthreads();
    if (t < 128) {
        const int slot = blockIdx.x & (NSLOT - 1);
        atomicAdd(&gsum[slot * 128 + t], bsum[t]);
        atomicAdd(&gsq[slot * 128 + t], bsq[t]);
    }
}

__global__ __launch_bounds__(128) void ks_v14(const float* __restrict__ gsum,
                                              const float* __restrict__ gsq,
                                              const float* __restrict__ g,
                                              const float* __restrict__ be,
                                              float* __restrict__ a,
                                              float* __restrict__ bb) {
    const int c = threadIdx.x;
    float S = 0.f, Q = 0.f;
    for (int s = 0; s < NSLOT; ++s) { S += gsum[s * 128 + c]; Q += gsq[s * 128 + c]; }
    const float mean = S / (float)NEDGE;
    const float var  = Q / (float)NEDGE - mean * mean;
    const float av   = g[c] * rsqrtf(var + BN_EPS);
    a[c]  = av;
    bb[c] = be[c] - mean * av;
}

// Y2 = relu(bn1(Y1)) @ W2 + b2 (MFMA), in place; accumulate BN2 stats.
__global__ __launch_bounds__(256, 6) void k2_v14(float* __restrict__ Y,
                                                 const float* __restrict__ a1,
                                                 const float* __restrict__ bb1,
                                                 const _Float16* __restrict__ W2p,
                                                 const float* __restrict__ b2,
                                                 float* __restrict__ gsum,
                                                 float* __restrict__ gsq) {
    __shared__ _Float16 Xs[32][136];
    __shared__ float bsum[128], bsq[128];
    const int t = threadIdx.x, lane = t & 63, w = t >> 6;
    const int e0 = blockIdx.x * 32;
    if (t < 128) { bsum[t] = 0.f; bsq[t] = 0.f; }
    for (int o = t; o < 32 * 32; o += 256) {   // vectorized staging
        int e = o >> 5, k4 = (o & 31) << 2;
        float4 v = *(const float4*)&Y[(size_t)(e0 + e) * 128 + k4];
        float4 av = *(const float4*)&a1[k4];
        float4 bv = *(const float4*)&bb1[k4];
        f16x4 s;
        s[0] = (_Float16)fmaxf(v.x * av.x + bv.x, 0.f);
        s[1] = (_Float16)fmaxf(v.y * av.y + bv.y, 0.f);
        s[2] = (_Float16)fmaxf(v.z * av.z + bv.z, 0.f);
        s[3] = (_Float16)fmaxf(v.w * av.w + bv.w, 0.f);
        *(f16x4*)&Xs[e][k4] = s;
    }
    __syncthreads();
    f32x4 acc[2][2] = {};
#pragma unroll
    for (int kk = 0; kk < 4; ++kk) {
        f16x8 a0 = *(const f16x8*)&Xs[(lane & 15)][kk * 32 + (lane >> 4) * 8];
        f16x8 a1f = *(const f16x8*)&Xs[16 + (lane & 15)][kk * 32 + (lane >> 4) * 8];
        f16x8 b0 = *(const f16x8*)(W2p + ((size_t)(kk * 8 + 2 * w) * 64 + lane) * 8);
        f16x8 b1v = *(const f16x8*)(W2p + ((size_t)(kk * 8 + 2 * w + 1) * 64 + lane) * 8);
        acc[0][0] = MFMA(a0, b0, acc[0][0]);
        acc[1][0] = MFMA(a1f, b0, acc[1][0]);
        acc[0][1] = MFMA(a0, b1v, acc[0][1]);
        acc[1][1] = MFMA(a1f, b1v, acc[1][1]);
    }
#pragma unroll
    for (int ct2 = 0; ct2 < 2; ++ct2) {
        const int c = (2 * w + ct2) * 16 + (lane & 15);
        const float bias = b2[c];
#pragma unroll
        for (int rt = 0; rt < 2; ++rt) {
            float s = 0.f, sq = 0.f;
#pragma unroll
            for (int r = 0; r < 4; ++r) {
                int e = rt * 16 + (lane >> 4) * 4 + r;
                float y = acc[rt][ct2][r] + bias;
                Y[(size_t)(e0 + e) * 128 + c] = y;
                s += y; sq += y * y;
            }
            atomicAdd(&bsum[c], s);
            atomicAdd(&bsq[c], sq);
        }
    }
    __syncthreads();
    if (t < 128) {
        const int slot = blockIdx.x & (NSLOT - 1);
        atomicAdd(&gsum[slot * 128 + t], bsum[t]);
        atomicAdd(&gsq[slot * 128 + t], bsq[t]);
    }
}

// out = relu(bn2(Y2)) @ W3m + hE @ WmTop + bfold (two fused MFMA GEMMs).
__global__ __launch_bounds__(256, 6) void k3_v14(float* __restrict__ Y,
                                                 const float* __restrict__ hE,
                                                 const float* __restrict__ a2,
                                                 const float* __restrict__ bb2,
                                                 const _Float16* __restrict__ W3mp,
                                                 const _Float16* __restrict__ Wmp,
                                                 const float* __restrict__ bfold) {
    __shared__ _Float16 Xs[32][136];
    __shared__ _Float16 Hes[32][136];
    const int t = threadIdx.x, lane = t & 63, w = t >> 6;
    const int e0 = blockIdx.x * 32;
    for (int o = t; o < 32 * 32; o += 256) {   // vectorized staging
        int e = o >> 5, k4 = (o & 31) << 2;
        float4 v = *(const float4*)&Y[(size_t)(e0 + e) * 128 + k4];
        float4 hv = *(const float4*)&hE[(size_t)(e0 + e) * 128 + k4];
        float4 av = *(const float4*)&a2[k4];
        float4 bv = *(const float4*)&bb2[k4];
        f16x4 s, h;
        s[0] = (_Float16)fmaxf(v.x * av.x + bv.x, 0.f);
        s[1] = (_Float16)fmaxf(v.y * av.y + bv.y, 0.f);
        s[2] = (_Float16)fmaxf(v.z * av.z + bv.z, 0.f);
        s[3] = (_Float16)fmaxf(v.w * av.w + bv.w, 0.f);
        h[0] = (_Float16)hv.x; h[1] = (_Float16)hv.y;
        h[2] = (_Float16)hv.z; h[3] = (_Float16)hv.w;
        *(f16x4*)&Xs[e][k4] = s;
        *(f16x4*)&Hes[e][k4] = h;
    }
    __syncthreads();
    f32x4 acc[2][2] = {};
#pragma unroll
    for (int kk = 0; kk < 4; ++kk) {
        f16x8 x0 = *(const f16x8*)&Xs[(lane & 15)][kk * 32 + (lane >> 4) * 8];
        f16x8 x1 = *(const f16x8*)&Xs[16 + (lane & 15)][kk * 32 + (lane >> 4) * 8];
        f16x8 h0 = *(const f16x8*)&Hes[(lane & 15)][kk * 32 + (lane >> 4) * 8];
        f16x8 h1 = *(const f16x8*)&Hes[16 + (lane & 15)][kk * 32 + (lane >> 4) * 8];
        f16x8 w30 = *(const f16x8*)(W3mp + ((size_t)(kk * 8 + 2 * w) * 64 + lane) * 8);
        f16x8 w31 = *(const f16x8*)(W3mp + ((size_t)(kk * 8 + 2 * w + 1) * 64 + lane) * 8);
        f16x8 wm0 = *(const f16x8*)(Wmp + ((size_t)(kk * 8 + 2 * w) * 64 + lane) * 8);
        f16x8 wm1 = *(const f16x8*)(Wmp + ((size_t)(kk * 8 + 2 * w + 1) * 64 + lane) * 8);
        acc[0][0] = MFMA(x0, w30, acc[0][0]);
        acc[1][0] = MFMA(x1, w30, acc[1][0]);
        acc[0][1] = MFMA(x0, w31, acc[0][1]);
        acc[1][1] = MFMA(x1, w31, acc[1][1]);
        acc[0][0] = MFMA(h0, wm0, acc[0][0]);
        acc[1][0] = MFMA(h1, wm0, acc[1][0]);
        acc[0][1] = MFMA(h0, wm1, acc[0][1]);
        acc[1][1] = MFMA(h1, wm1, acc[1][1]);
    }
#pragma unroll
    for (int ct2 = 0; ct2 < 2; ++ct2) {
        const int c = (2 * w + ct2) * 16 + (lane & 15);
        const float bias = bfold[c];
#pragma unroll
        for (int rt = 0; rt < 2; ++rt)
#pragma unroll
            for (int r = 0; r < 4; ++r) {
                int e = rt * 16 + (lane >> 4) * 4 + r;
                Y[(size_t)(e0 + e) * 128 + c] = acc[rt][ct2][r] + bias;
            }
    }
}

extern "C" void kernel_launch(void* const* d_in, const int* in_sizes, int n_in,
                              void* d_out, int out_size, void* d_ws, size_t ws_size,
                              hipStream_t stream) {
    const float* hV    = (const float*)d_in[0];
    const float* hE    = (const float*)d_in[1];
    const float* rot   = (const float*)d_in[2];
    const float* trans = (const float*)d_in[3];
    const float* rbf   = (const float*)d_in[4];
    const float* Wva   = (const float*)d_in[6];
    const float* bva   = (const float*)d_in[7];
    const float* Wvd   = (const float*)d_in[8];
    const float* bvd   = (const float*)d_in[9];
    const float* W1    = (const float*)d_in[10];
    const float* b1    = (const float*)d_in[11];
    const float* g1    = (const float*)d_in[12];
    const float* be1   = (const float*)d_in[13];
    const float* W2    = (const float*)d_in[14];
    const float* b2    = (const float*)d_in[15];
    const float* g2    = (const float*)d_in[16];
    const float* be2   = (const float*)d_in[17];
    const float* W3    = (const float*)d_in[18];
    const float* b3    = (const float*)d_in[19];
    const float* Wm    = (const float*)d_in[20];
    const float* bm    = (const float*)d_in[21];
    const long long* eidx = (const long long*)d_in[22];

    float* ws    = (float*)d_ws;
    float* Vloc  = ws;
    float* W3m   = ws + 1920000;
    float* bfold = W3m + 16384;
    float* a1    = bfold + 128;
    float* bb1   = a1 + 128;
    float* a2    = bb1 + 128;
    float* bb2   = a2 + 128;
    float* slots = bb2 + 128;
    float* gsum1 = slots;
    float* gsq1  = slots + NSLOT * 128;
    float* gsum2 = slots + 2 * NSLOT * 128;
    float* gsq2  = slots + 3 * NSLOT * 128;
    _Float16* W1p    = (_Float16*)(slots + 4 * NSLOT * 128);
    _Float16* Wvdp   = W1p + 57344;
    _Float16* W2p    = Wvdp + 16384;
    _Float16* W3mp   = W2p + 16384;
    _Float16* Wmp    = W3mp + 16384;
    _Float16* Wvap   = Wmp + 16384;
    _Float16* WvapLo = Wvap + 16384;
    float* Y     = (float*)d_out;

    hipMemsetAsync(slots, 0, (size_t)4 * NSLOT * 128 * sizeof(float), stream);
    kp_v14<<<64, 256, 0, stream>>>(Wva, Wvap, 128, 96, 128, 0);
    kp_v14<<<64, 256, 0, stream>>>(Wva, WvapLo, 128, 96, 128, 1);
    kw_v14<<<65, 256, 0, stream>>>(W3, b3, Wm, bm, W3m, bfold);
    kv_v14<<<NATOM / 32, 256, 0, stream>>>(hV, Wvap, WvapLo, bva, Vloc);
    kp_v14<<<224, 256, 0, stream>>>(W1, W1p, 441, 128, 448, 0);
    kp_v14<<<64, 256, 0, stream>>>(Wvd, Wvdp, 128, 96, 128, 0);
    kp_v14<<<64, 256, 0, stream>>>(W2, W2p, 128, 128, 128, 0);
    kp_v14<<<64, 256, 0, stream>>>(W3m, W3mp, 128, 128, 128, 0);
    kp_v14<<<64, 256, 0, stream>>>(Wm, Wmp, 128, 128, 128, 0);
    kf_v14<<<NEDGE / 32, 256, 0, stream>>>(hE, rot, trans, rbf, eidx, Vloc,
                                           Wvdp, bvd, W1p, b1, Y, gsum1, gsq1);
    ks_v14<<<1, 128, 0, stream>>>(gsum1, gsq1, g1, be1, a1, bb1);
    k2_v14<<<NEDGE / 32, 256, 0, stream>>>(Y, a1, bb1, W2p, b2, gsum2, gsq2);
    ks_v14<<<1, 128, 0, stream>>>(gsum2, gsq2, g2, be2, a2, bb2);
    k3_v14<<<NEDGE / 32, 256, 0, stream>>>(Y, hE, a2, bb2, W3mp, Wmp, bfold);
}